// Round 1
// baseline (869.603 us; speedup 1.0000x reference)
//
#include <hip/hip_runtime.h>

#define M_ROWS   500000
#define D_COLS   128
#define E_EDGES  8000000
#define NGROUPS  (M_ROWS / 8)   // 62500 groups of 8 rows
#define NE4      (E_EDGES / 4)  // 2,000,000 int4

// ws layout: float total[128]; int deg[M_ROWS]
// Block = 256 threads: thread t -> col4 = t&31 (float4 column chunk), sub = t>>5 (row within group of 8)

__global__ void colsum_kernel(const float* __restrict__ emb, float* __restrict__ total) {
    const int t = threadIdx.x;
    const int col4 = t & 31;
    const int sub  = t >> 5;
    float4 acc = make_float4(0.f, 0.f, 0.f, 0.f);
    for (int g = blockIdx.x; g < NGROUPS; g += gridDim.x) {
        const long row = (long)g * 8 + sub;
        const float4 v = ((const float4*)(emb + row * D_COLS))[col4];
        acc.x += v.x; acc.y += v.y; acc.z += v.z; acc.w += v.w;
    }
    __shared__ float4 red[256];
    red[t] = acc;
    __syncthreads();
    if (sub == 0) {
        float4 s = red[col4];
        #pragma unroll
        for (int j = 1; j < 8; ++j) {
            const float4 v = red[j * 32 + col4];
            s.x += v.x; s.y += v.y; s.z += v.z; s.w += v.w;
        }
        atomicAdd(&total[col4 * 4 + 0], s.x);
        atomicAdd(&total[col4 * 4 + 1], s.y);
        atomicAdd(&total[col4 * 4 + 2], s.z);
        atomicAdd(&total[col4 * 4 + 3], s.w);
    }
}

__global__ void degree_kernel(const int* __restrict__ rows, int* __restrict__ deg) {
    const int idx    = blockIdx.x * blockDim.x + threadIdx.x;
    const int stride = gridDim.x * blockDim.x;
    const int4* r4 = (const int4*)rows;
    for (int i = idx; i < NE4; i += stride) {
        const int4 v = r4[i];
        atomicAdd(&deg[v.x], 1);
        atomicAdd(&deg[v.y], 1);
        atomicAdd(&deg[v.z], 1);
        atomicAdd(&deg[v.w], 1);
    }
}

__global__ void update_kernel(const float* __restrict__ emb, const float* __restrict__ total,
                              const int* __restrict__ deg, float* __restrict__ out) {
    __shared__ float4 t4s[32];
    const int t = threadIdx.x;
    if (t < 32) t4s[t] = ((const float4*)total)[t];
    __syncthreads();
    const int col4 = t & 31;
    const int sub  = t >> 5;
    const float4 tt = t4s[col4];
    for (int g = blockIdx.x; g < NGROUPS; g += gridDim.x) {
        const long row = (long)g * 8 + sub;
        const float invd = 1.0f / (1.0f + (float)deg[row]);
        const float4 v = ((const float4*)(emb + row * D_COLS))[col4];
        float4 o;
        o.x = (v.x + tt.x) * (1.0f - tt.x * invd);
        o.y = (v.y + tt.y) * (1.0f - tt.y * invd);
        o.z = (v.z + tt.z) * (1.0f - tt.z * invd);
        o.w = (v.w + tt.w) * (1.0f - tt.w * invd);
        ((float4*)(out + row * D_COLS))[col4] = o;
    }
}

extern "C" void kernel_launch(void* const* d_in, const int* in_sizes, int n_in,
                              void* d_out, int out_size, void* d_ws, size_t ws_size,
                              hipStream_t stream) {
    const float* emb  = (const float*)d_in[0];
    const int*   rows = (const int*)d_in[1];
    float* out   = (float*)d_out;
    float* total = (float*)d_ws;
    int*   deg   = (int*)((char*)d_ws + 128 * sizeof(float));

    // zero total + deg (ws is re-poisoned to 0xAA before every timed launch)
    hipMemsetAsync(d_ws, 0, (128 + M_ROWS) * sizeof(int), stream);

    colsum_kernel<<<1024, 256, 0, stream>>>(emb, total);
    degree_kernel<<<1024, 256, 0, stream>>>(rows, deg);
    update_kernel<<<2048, 256, 0, stream>>>(emb, total, deg, out);
}

// Round 2
// 778.634 us; speedup vs baseline: 1.1168x; 1.1168x over previous
//
#include <hip/hip_runtime.h>

#define M_ROWS   500000
#define D_COLS   128
#define E_EDGES  8000000
#define NGROUPS  (M_ROWS / 8)   // 62500 groups of 8 rows
#define NE4      (E_EDGES / 4)  // 2,000,000 int4
#define NPBLK    2048           // colsum stage-A blocks (partials per column)

// ws layout:    int deg[M_ROWS]; float total[128]
// d_out scratch: float partials[128][NPBLK]  (1 MB, overwritten by update_kernel at the end)

__global__ void colsum_partial_kernel(const float* __restrict__ emb, float* __restrict__ partials) {
    const int t = threadIdx.x;
    const int col4 = t & 31;   // which float4 chunk of the 128 columns
    const int sub  = t >> 5;   // row within group of 8
    float4 acc = make_float4(0.f, 0.f, 0.f, 0.f);
    for (int g = blockIdx.x; g < NGROUPS; g += gridDim.x) {
        const long row = (long)g * 8 + sub;
        const float4 v = ((const float4*)(emb + row * D_COLS))[col4];
        acc.x += v.x; acc.y += v.y; acc.z += v.z; acc.w += v.w;
    }
    __shared__ float4 red[256];
    red[t] = acc;
    __syncthreads();
    if (sub == 0) {
        float4 s = red[col4];
        #pragma unroll
        for (int j = 1; j < 8; ++j) {
            const float4 v = red[j * 32 + col4];
            s.x += v.x; s.y += v.y; s.z += v.z; s.w += v.w;
        }
        // col-major partials: partials[c][bid], no atomics
        partials[(col4 * 4 + 0) * NPBLK + blockIdx.x] = s.x;
        partials[(col4 * 4 + 1) * NPBLK + blockIdx.x] = s.y;
        partials[(col4 * 4 + 2) * NPBLK + blockIdx.x] = s.z;
        partials[(col4 * 4 + 3) * NPBLK + blockIdx.x] = s.w;
    }
}

// one block per column: reduce NPBLK partials -> total[col]
__global__ void colsum_final_kernel(const float* __restrict__ partials, float* __restrict__ total) {
    const int col = blockIdx.x;
    const int t = threadIdx.x;
    float s = 0.f;
    #pragma unroll
    for (int k = 0; k < NPBLK / 256; ++k)
        s += partials[col * NPBLK + k * 256 + t];
    __shared__ float red[256];
    red[t] = s;
    __syncthreads();
    for (int off = 128; off > 0; off >>= 1) {
        if (t < off) red[t] += red[t + off];
        __syncthreads();
    }
    if (t == 0) total[col] = red[0];
}

__global__ void degree_kernel(const int* __restrict__ rows, int* __restrict__ deg) {
    const int idx    = blockIdx.x * blockDim.x + threadIdx.x;
    const int stride = gridDim.x * blockDim.x;
    const int4* r4 = (const int4*)rows;
    for (int i = idx; i < NE4; i += stride) {
        const int4 v = r4[i];
        atomicAdd(&deg[v.x], 1);
        atomicAdd(&deg[v.y], 1);
        atomicAdd(&deg[v.z], 1);
        atomicAdd(&deg[v.w], 1);
    }
}

__global__ void update_kernel(const float* __restrict__ emb, const float* __restrict__ total,
                              const int* __restrict__ deg, float* __restrict__ out) {
    __shared__ float4 t4s[32];
    const int t = threadIdx.x;
    if (t < 32) t4s[t] = ((const float4*)total)[t];
    __syncthreads();
    const int col4 = t & 31;
    const int sub  = t >> 5;
    const float4 tt = t4s[col4];
    for (int g = blockIdx.x; g < NGROUPS; g += gridDim.x) {
        const long row = (long)g * 8 + sub;
        const float invd = 1.0f / (1.0f + (float)deg[row]);
        const float4 v = ((const float4*)(emb + row * D_COLS))[col4];
        float4 o;
        o.x = (v.x + tt.x) * (1.0f - tt.x * invd);
        o.y = (v.y + tt.y) * (1.0f - tt.y * invd);
        o.z = (v.z + tt.z) * (1.0f - tt.z * invd);
        o.w = (v.w + tt.w) * (1.0f - tt.w * invd);
        ((float4*)(out + row * D_COLS))[col4] = o;
    }
}

extern "C" void kernel_launch(void* const* d_in, const int* in_sizes, int n_in,
                              void* d_out, int out_size, void* d_ws, size_t ws_size,
                              hipStream_t stream) {
    const float* emb  = (const float*)d_in[0];
    const int*   rows = (const int*)d_in[1];
    float* out      = (float*)d_out;
    float* partials = (float*)d_out;                       // scratch, overwritten by update
    int*   deg      = (int*)d_ws;
    float* total    = (float*)((char*)d_ws + M_ROWS * sizeof(int));

    hipMemsetAsync(deg, 0, M_ROWS * sizeof(int), stream);  // only deg needs zeroing

    degree_kernel<<<4096, 256, 0, stream>>>(rows, deg);
    colsum_partial_kernel<<<NPBLK, 256, 0, stream>>>(emb, partials);
    colsum_final_kernel<<<D_COLS, 256, 0, stream>>>(partials, total);
    update_kernel<<<4096, 256, 0, stream>>>(emb, total, deg, out);
}